// Round 9
// baseline (8872.610 us; speedup 1.0000x reference)
//
#include <hip/hip_runtime.h>
#include <hip/hip_bf16.h>
#include <hip/hip_fp16.h>

// ---------------------------------------------------------------------------
// 4-layer LSTM (H=1024, B=64, T=256) + FC, persistent pipelined kernel.
// R13: ZERO barriers in the fresh-mode step loop.
//   - bar1 replaced by parity double-buffered partials (partial[s&1][wave])
//     + LDS ready-flags (release store after partial write; EW spins lanes
//     0-3 on all 4 flags >= s). Safety invariant: wave w writes par_{s+1}
//     only after its EW(s) spin saw all flags = s; flag[w']=s implies (prog
//     order) w' finished EW(s-1) - the only reader of par_{s+1}=par_{s-1}.
//   - bar2 + tid0 publish replaced by PER-WAVE publish: flag line = 4 ints;
//     each wave release-stores its int = s (release drains that wave's
//     h-stores to IF$). Consumers poll min-of-4 (one line fill).
//   - LDS: w_hh ks 0..17 staged (73728 B) + 2x4x8192 partials + flag line;
//     hh waves split even/odd ks -> balanced 9 LDS + 7 global b-ks each.
//   Fallback (!fresh): R12 structure (wide polls, 2 barriers, tid0 4-int
//   publish, sc loads) retained.
// ---------------------------------------------------------------------------

#define H      1024
#define BATCH  64
#define T      256
#define RINGN  8

typedef _Float16 f16x8 __attribute__((ext_vector_type(8)));
typedef _Float16 f16x4 __attribute__((ext_vector_type(4)));
typedef float    f32x4 __attribute__((ext_vector_type(4)));

// ws layout (bytes)
#define WPACK_HH_SZ  (4ull*64*32*4*64*8*2)           // 33554432: [l][wg][ks][nt][lane][8] f16
#define WPACK_IH_SZ  (3ull*64*32*4*64*8*2)           // 25165824
#define HRING_OFF    (WPACK_HH_SZ + WPACK_IH_SZ)     // 58720256
#define SLOT_ELEMS   65536                           // per (l,slot): 64 batch x 1024 units f16
#define SLOT_BYTES   131072ull
#define CNT_INTS     (4*257*16)                      // flag/cnt2 region, 64B-padded entries
#define CNT_BYTES    ((unsigned long long)CNT_INTS*4)

// LDS layout (bytes)
#define WHH_LDS_KS     18
#define WHH_LDS_BYTES  (WHH_LDS_KS*4*64*16)          // 73728
#define PART_OFF       WHH_LDS_BYTES                 // partials: 2 par x 4 waves x 8192
#define FLG_OFF        (PART_OFF + 65536)            // 8 flags x 64B = 512
#define LDS_TOTAL      (FLG_OFF + 512)               // 139776 <= 147456

__host__ __device__ __forceinline__ unsigned long long ring_bytes(int nslot) {
  return 4ull*(unsigned)nslot*SLOT_BYTES;
}
__device__ __forceinline__ int cidx(int l, int s) { return (l*257 + s)*16; }
// per-producer flag line: one 64B line per (layer, wg); ints 0..3 = per-wave
__device__ __forceinline__ int fidx(int l, int w) { return (l*64 + w)*16; }

// fresh mode: bit-reversed slot index kills any sequential-prefetch adjacency
__device__ __forceinline__ int aslot(int s, int fresh) {
  if (!fresh) return s & 7;
  return (s >= 256) ? 256 : (int)(__brev((unsigned)s) >> 24);
}

__device__ __forceinline__ void wait_eq64(int* p) {
  int it = 0;
  while (__hip_atomic_load(p, __ATOMIC_RELAXED, __HIP_MEMORY_SCOPE_AGENT) < 64) {
    __builtin_amdgcn_s_sleep(1);
    if (++it > 100000000) break;   // failsafe: never hang the harness
  }
}

// poll one producer's 4 per-wave flags until all >= tgt (one line fill/iter)
__device__ __forceinline__ void wait_all4_ge(const int* p, int tgt) {
  int it = 0;
  for (;;) {
    int v0 = __hip_atomic_load(p + 0, __ATOMIC_RELAXED, __HIP_MEMORY_SCOPE_AGENT);
    int v1 = __hip_atomic_load(p + 1, __ATOMIC_RELAXED, __HIP_MEMORY_SCOPE_AGENT);
    int v2 = __hip_atomic_load(p + 2, __ATOMIC_RELAXED, __HIP_MEMORY_SCOPE_AGENT);
    int v3 = __hip_atomic_load(p + 3, __ATOMIC_RELAXED, __HIP_MEMORY_SCOPE_AGENT);
    if (v0 >= tgt && v1 >= tgt && v2 >= tgt && v3 >= tgt) break;
    __builtin_amdgcn_s_sleep(1);
    if (++it > 50000000) break;    // failsafe
  }
}

// LDS flag spin (workgroup scope, acquire so later ds_reads see partials)
__device__ __forceinline__ void lds_wait_ge(const int* p, int tgt) {
  int it = 0;
  while (__hip_atomic_load(p, __ATOMIC_ACQUIRE, __HIP_MEMORY_SCOPE_WORKGROUP) < tgt) {
    if (++it > 200000000) break;   // failsafe
  }
}

__device__ __forceinline__ f16x8 load_h8_sc(const _Float16* p) {
  const unsigned long long* q = (const unsigned long long*)p;
  unsigned long long lo = __hip_atomic_load(q,     __ATOMIC_RELAXED, __HIP_MEMORY_SCOPE_AGENT);
  unsigned long long hi = __hip_atomic_load(q + 1, __ATOMIC_RELAXED, __HIP_MEMORY_SCOPE_AGENT);
  union { unsigned long long u[2]; f16x8 v; } c;
  c.u[0] = lo; c.u[1] = hi;
  return c.v;
}

// --- pack weights fp32 -> fp16 MFMA-fragment layout; zero h ring slot 0
__global__ void pack_kernel(const float* __restrict__ w_ih_rest,
                            const float* __restrict__ w_hh,
                            char* __restrict__ ws, int nslot)
{
  const long long NS_HH = 4ll*64*32*4*64;   // 2097152
  const long long NS_IH = 3ll*64*32*4*64;   // 1572864
  const long long NS_HZ = 4ll*8192;         // uint4 slots to zero slot-0 of each layer ring
  const long long NTOT  = NS_HH + NS_IH + NS_HZ;
  _Float16* whh_dst = (_Float16*)ws;
  _Float16* wih_dst = (_Float16*)(ws + WPACK_HH_SZ);
  for (long long i = blockIdx.x*(long long)blockDim.x + threadIdx.x; i < NTOT;
       i += (long long)gridDim.x*blockDim.x) {
    if (i < NS_HH + NS_IH) {
      const bool is_hh = (i < NS_HH);
      long long slot = is_hh ? i : (i - NS_HH);
      long long j = slot;
      int lane = (int)(j & 63); j >>= 6;
      int nt   = (int)(j & 3);  j >>= 2;
      int ks   = (int)(j & 31); j >>= 5;
      int wg   = (int)(j & 63); j >>= 6;
      int l    = (int)j;
      int row = nt*1024 + wg*16 + (lane & 15);      // global gate row (nt = gate: i,f,g,o)
      int col = ks*32 + (lane >> 4)*8;
      const float* src = (is_hh ? w_hh : w_ih_rest) + ((long long)l*4096 + row)*1024 + col;
      f16x8 v;
      #pragma unroll
      for (int e = 0; e < 8; e++) v[e] = (_Float16)src[e];
      *(f16x8*)((is_hh ? whh_dst : wih_dst) + slot*8) = v;
    } else {
      long long j = i - (NS_HH + NS_IH);
      long long l = j >> 13;            // /8192
      long long off = j & 8191;
      uint4 z = make_uint4(0,0,0,0);
      ((uint4*)(ws + HRING_OFF))[(l*(long long)nslot)*8192 + off] = z;  // zero h[l][slot0]
    }
  }
}

__global__ __launch_bounds__(256, 1) void lstm_main(
    const float* __restrict__ x,
    const float* __restrict__ wih0,
    const float* __restrict__ bih,
    const float* __restrict__ bhh,
    char* __restrict__ ws, int nslot, int fresh)
{
  // one-time agent acquire: invalidate stale L1/L2 lines from prior replays
  __builtin_amdgcn_fence(__ATOMIC_ACQUIRE, "agent");

  extern __shared__ char lds[];
  _Float16* whh_lds = (_Float16*)lds;                 // ks 0..17 frag layout
  _Float16* bufs    = (_Float16*)(lds + PART_OFF);    // [par][wave] 4096 f16 each
  int*      ldsflg  = (int*)(lds + FLG_OFF);          // (par*4+wave)*16

  const int l   = blockIdx.x >> 6;
  const int wg  = blockIdx.x & 63;
  const int tid = threadIdx.x;
  const int wave = tid >> 6;
  const int lane = tid & 63;

  const _Float16* wpack_hh = (const _Float16*)ws + (size_t)(l*64 + wg)*65536;
  const _Float16* wpack_ih = (l > 0)
      ? (const _Float16*)(ws + WPACK_HH_SZ) + (size_t)((l-1)*64 + wg)*65536
      : wpack_hh;  // unused for l==0
  _Float16* hring = (_Float16*)(ws + HRING_OFF);
  int* cnt  = (int*)(ws + HRING_OFF + ring_bytes(nslot));   // per-producer flag lines
  int* cnt2 = cnt + CNT_INTS;                               // fallback backpressure

  // stage w_hh ks 0..17 into LDS; init LDS flags
  {
    const uint4* src = (const uint4*)wpack_hh;
    uint4* dst = (uint4*)whh_lds;
    for (int i = tid; i < WHH_LDS_BYTES/16; i += 256) dst[i] = src[i];
    if (tid < 8) ldsflg[tid*16] = 0;
  }

  // elementwise ownership: thread -> (batch b_ew, 4 consecutive hidden units u0..u0+3)
  const int b_ew = tid >> 2;
  const int u0   = (tid & 3) * 4;
  float cst[4] = {0.f, 0.f, 0.f, 0.f};
  float bias[4][4];            // [item][gate]
  float wx0[4][4], wx1[4][4];  // layer-0 input weights (K=2 handled in VALU)
  #pragma unroll
  for (int ii = 0; ii < 4; ii++) {
    #pragma unroll
    for (int g = 0; g < 4; g++) {
      int row = g*1024 + wg*16 + u0 + ii;
      bias[ii][g] = bih[l*4096 + row] + bhh[l*4096 + row];
      if (l == 0) { wx0[ii][g] = wih0[row*2]; wx1[ii][g] = wih0[row*2 + 1]; }
      else        { wx0[ii][g] = 0.f;         wx1[ii][g] = 0.f; }
    }
  }
  __syncthreads();   // staging + flag init visible

  const int m_row = lane & 15, quad = lane >> 4;

  for (int s = 1; s <= T; s++) {
    const int par = s & 1;

    if (fresh) {
      // per-wave dataflow polls only over the producers this wave's k-range reads
      if (l == 0) {
        if (lane < 16) {
          int wg2 = 2*(wave + 4*(lane >> 1)) + (lane & 1);   // ks=4i+wave producers
          wait_all4_ge(cnt + fidx(0, wg2), s - 1);
        }
      } else if (wave < 2) {
        if (lane < 32) wait_all4_ge(cnt + fidx(l-1, wave*32 + lane), s);
      } else {
        if (lane < 32) {
          int wg2 = 4*(lane >> 1) + (lane & 1) + 2*(wave - 2);  // even/odd ks producers
          wait_all4_ge(cnt + fidx(l, wg2), s - 1);
        }
      }
    } else {
      if (wave == 0) {
        wait_all4_ge(cnt + fidx(l, lane), s - 1);
      } else if (wave == 1) {
        if (l > 0) wait_all4_ge(cnt + fidx(l - 1, lane), s);
      } else if (tid == 128) {
        if (l < 3 && s > RINGN) wait_eq64(&cnt2[cidx(l, s-RINGN)]);
      }
      __syncthreads();
    }

    // A source: ih waves read h_below[s]; hh waves read h_own[s-1]
    const _Float16* asrc = (l > 0 && wave < 2)
        ? hring + ((size_t)(l-1)*nslot + aslot(s,   fresh))*SLOT_ELEMS
        : hring + ((size_t)l*nslot     + aslot(s-1, fresh))*SLOT_ELEMS;

    f32x4 acc[4][4];
    #pragma unroll
    for (int mt = 0; mt < 4; mt++)
      #pragma unroll
      for (int nt = 0; nt < 4; nt++) acc[mt][nt] = (f32x4){0.f, 0.f, 0.f, 0.f};

    auto kb_lds = [&](int ks, bool plain) {
      const int kb = ks*32 + quad*8;
      f16x8 a[4], bb[4];
      #pragma unroll
      for (int mt = 0; mt < 4; mt++) {
        const _Float16* ap = asrc + (size_t)(mt*16 + m_row)*1024 + kb;
        a[mt] = plain ? *(const f16x8*)ap : load_h8_sc(ap);
      }
      #pragma unroll
      for (int nt = 0; nt < 4; nt++)
        bb[nt] = *(const f16x8*)(whh_lds + ((ks*4 + nt)*64 + lane)*8);
      #pragma unroll
      for (int mt = 0; mt < 4; mt++)
        #pragma unroll
        for (int nt = 0; nt < 4; nt++)
          acc[mt][nt] = __builtin_amdgcn_mfma_f32_16x16x32_f16(a[mt], bb[nt], acc[mt][nt], 0, 0, 0);
    };
    auto kb_glob = [&](int ks, const _Float16* bsrc, bool plain) {
      const int kb = ks*32 + quad*8;
      f16x8 a[4], bb[4];
      #pragma unroll
      for (int mt = 0; mt < 4; mt++) {
        const _Float16* ap = asrc + (size_t)(mt*16 + m_row)*1024 + kb;
        a[mt] = plain ? *(const f16x8*)ap : load_h8_sc(ap);
      }
      #pragma unroll
      for (int nt = 0; nt < 4; nt++)
        bb[nt] = *(const f16x8*)(bsrc + ((size_t)(ks*4 + nt)*64 + lane)*8);
      #pragma unroll
      for (int mt = 0; mt < 4; mt++)
        #pragma unroll
        for (int nt = 0; nt < 4; nt++)
          acc[mt][nt] = __builtin_amdgcn_mfma_f32_16x16x32_f16(a[mt], bb[nt], acc[mt][nt], 0, 0, 0);
    };

    const bool pl = (fresh != 0);
    if (l == 0) {
      // all waves hh: ks = 4*i + wave
      if (wave < 2) {
        #pragma unroll 4
        for (int i = 0; i < 5; i++) kb_lds(4*i + wave, pl);            // ks<=17
        #pragma unroll
        for (int i = 5; i < 8; i++) kb_glob(4*i + wave, wpack_hh, pl); // 20..29
      } else {
        #pragma unroll 4
        for (int i = 0; i < 4; i++) kb_lds(4*i + wave, pl);            // ks<=15
        #pragma unroll 4
        for (int i = 4; i < 8; i++) kb_glob(4*i + wave, wpack_hh, pl); // 18..31
      }
    } else if (wave < 2) {
      #pragma unroll 4
      for (int i = 0; i < 16; i++) kb_glob(wave*16 + i, wpack_ih, pl);
    } else {
      const int o = wave - 2;   // even/odd ks split
      #pragma unroll 4
      for (int i = 0; i < 9; i++) kb_lds(2*i + o, pl);                 // ks 0..17
      #pragma unroll
      for (int i = 9; i < 16; i++) kb_glob(2*i + o, wpack_hh, pl);     // ks 18..31
    }

    // partial write to this step's parity buffer
    {
      _Float16* mybuf = bufs + ((size_t)par*4 + wave)*4096;
      #pragma unroll
      for (int mt = 0; mt < 4; mt++)
        #pragma unroll
        for (int nt = 0; nt < 4; nt++) {
          f16x4 v;
          #pragma unroll
          for (int e = 0; e < 4; e++) v[e] = (_Float16)acc[mt][nt][e];
          *(f16x4*)(mybuf + ((mt*4 + nt)*64 + lane)*4) = v;
        }
    }

    if (fresh) {
      // release: drains this wave's ds_writes, then flag
      if (lane == 0)
        __hip_atomic_store(ldsflg + (par*4 + wave)*16, s,
                           __ATOMIC_RELEASE, __HIP_MEMORY_SCOPE_WORKGROUP);
      // EW gate: all 4 partials of step s ready
      if (lane < 4)
        lds_wait_ge(ldsflg + (par*4 + lane)*16, s);
    } else {
      if (tid == 0 && l > 0)
        __hip_atomic_fetch_add(&cnt2[cidx(l-1, s)], 1, __ATOMIC_RELAXED, __HIP_MEMORY_SCOPE_AGENT);
      __syncthreads();   // bar1
    }

    // elementwise gates -> c,h  (fp32); sums the 4 parity partials
    {
      const _Float16* base = bufs + (size_t)par*4*4096;
      const int mt = b_ew >> 4, q = (b_ew & 15) >> 2, reg = b_ew & 3;
      float xs0 = 0.f, xs1 = 0.f;
      if (l == 0) {
        xs0 = x[((size_t)b_ew*T + (s-1))*2];
        xs1 = x[((size_t)b_ew*T + (s-1))*2 + 1];
      }
      f16x4 hv;
      #pragma unroll
      for (int ii = 0; ii < 4; ii++) {
        const int u = u0 + ii;
        float pre[4];
        #pragma unroll
        for (int g = 0; g < 4; g++) {
          int idx = ((mt*4 + g)*64 + (u + 16*q))*4 + reg;
          pre[g] = (float)base[idx] + (float)base[4096 + idx]
                 + (float)base[8192 + idx] + (float)base[12288 + idx]
                 + bias[ii][g] + wx0[ii][g]*xs0 + wx1[ii][g]*xs1;
        }
        float ig = 1.f/(1.f + __expf(-pre[0]));
        float fg = 1.f/(1.f + __expf(-pre[1]));
        float gg = 2.f/(1.f + __expf(-2.f*pre[2])) - 1.f;
        float og = 1.f/(1.f + __expf(-pre[3]));
        float c  = fg*cst[ii] + ig*gg;
        cst[ii] = c;
        float th = 2.f/(1.f + __expf(-2.f*c)) - 1.f;
        hv[ii] = (_Float16)(og*th);
      }
      _Float16* hdst = hring + ((size_t)l*nslot + aslot(s, fresh))*SLOT_ELEMS
                     + (size_t)b_ew*1024 + wg*16 + u0;
      union { f16x4 v; unsigned long long u; } cv; cv.v = hv;
      // sc write-through: IF$ (coherence point) holds the authoritative copy
      __hip_atomic_store((unsigned long long*)hdst, cv.u,
                         __ATOMIC_RELAXED, __HIP_MEMORY_SCOPE_AGENT);
    }

    if (fresh) {
      // per-wave publish: release drains this wave's h-stores to IF$, then flag
      if (lane == 0)
        __hip_atomic_store(cnt + fidx(l, wg) + wave, s,
                           __ATOMIC_RELEASE, __HIP_MEMORY_SCOPE_AGENT);
    } else {
      __syncthreads();   // bar2: h stores acked before publish
      if (tid == 0) {
        __hip_atomic_store(cnt + fidx(l, wg) + 0, s, __ATOMIC_RELAXED, __HIP_MEMORY_SCOPE_AGENT);
        __hip_atomic_store(cnt + fidx(l, wg) + 1, s, __ATOMIC_RELAXED, __HIP_MEMORY_SCOPE_AGENT);
        __hip_atomic_store(cnt + fidx(l, wg) + 2, s, __ATOMIC_RELAXED, __HIP_MEMORY_SCOPE_AGENT);
        __hip_atomic_store(cnt + fidx(l, wg) + 3, s, __ATOMIC_RELAXED, __HIP_MEMORY_SCOPE_AGENT);
      }
    }
  }
}

__global__ void fc_kernel(const char* __restrict__ ws,
                          const float* __restrict__ fcw,
                          const float* __restrict__ fcb,
                          float* __restrict__ out, int nslot, int fresh)
{
  const _Float16* h3 = (const _Float16*)(ws + HRING_OFF)
                     + ((size_t)3*nslot + aslot(T, fresh))*SLOT_ELEMS;  // layer 3, t=256
  __shared__ float red[256];
  const int tid = threadIdx.x;
  const int b = tid >> 2, p = tid & 3;
  float sum = 0.f;
  for (int j = p*256; j < p*256 + 256; j++)
    sum += fcw[j] * (float)h3[(size_t)b*1024 + j];
  red[tid] = sum;
  __syncthreads();
  if (p == 0)
    out[b] = red[tid] + red[tid+1] + red[tid+2] + red[tid+3] + fcb[0];
}

extern "C" void kernel_launch(void* const* d_in, const int* in_sizes, int n_in,
                              void* d_out, int out_size, void* d_ws, size_t ws_size,
                              hipStream_t stream)
{
  const float* x    = (const float*)d_in[0];
  const float* wih0 = (const float*)d_in[1];
  const float* wihr = (const float*)d_in[2];
  const float* whh  = (const float*)d_in[3];
  const float* bih  = (const float*)d_in[4];
  const float* bhh  = (const float*)d_in[5];
  const float* fcw  = (const float*)d_in[6];
  const float* fcb  = (const float*)d_in[7];
  float* out = (float*)d_out;
  char* ws = (char*)d_ws;
  (void)in_sizes; (void)n_in; (void)out_size;

  const unsigned long long ws_big   = HRING_OFF + ring_bytes(257) + 2*CNT_BYTES; // ~193.6 MB
  const unsigned long long ws_small = HRING_OFF + ring_bytes(8)   + 2*CNT_BYTES; // ~63 MB
  if (ws_size < ws_small) return;
  const int fresh = (ws_size >= ws_big) ? 1 : 0;
  const int nslot = fresh ? 257 : 8;

  // opt-in to 147456 B dynamic LDS (host-side, idempotent, capture-safe)
  hipFuncSetAttribute(reinterpret_cast<const void*>(lstm_main),
                      hipFuncAttributeMaxDynamicSharedMemorySize, 147456);

  hipMemsetAsync(ws + HRING_OFF + ring_bytes(nslot), 0, (size_t)(2*CNT_BYTES), stream);
  pack_kernel<<<512, 256, 0, stream>>>(wihr, whh, ws, nslot);
  lstm_main<<<256, 256, 147456, stream>>>(x, wih0, bih, bhh, ws, nslot, fresh);
  fc_kernel<<<1, 256, 0, stream>>>(ws, fcw, fcb, out, nslot, fresh);
}

// Round 10
// 3408.366 us; speedup vs baseline: 2.6032x; 2.6032x over previous
//
#include <hip/hip_runtime.h>
#include <hip/hip_bf16.h>
#include <hip/hip_fp16.h>

// ---------------------------------------------------------------------------
// 4-layer LSTM (H=1024, B=64, T=256) + FC, persistent pipelined kernel.
// R14: R12 reverted (proven 3422us: dataflow waits, unroll-4, 4 partial bufs,
//      2 barriers/step) with ONE change: FULL w_hh in LDS via the 160 KiB
//      workgroup LDS opt-in (163840 = 32 ks x 4096 + 4 x 8192 partials).
//      Removes R12's wave-3 spill (4 global hh b-ks on the straggler wave,
//      every step) -> hh GEMM is pure LDS-B; wave 2: ks 0-15, wave 3: 16-31.
//      R13 post-mortem: shrinking w_hh LDS coverage (28->18 ks) put ~8MB/step
//      of hh b-reads on the critical chain (+5.5ms) - this round goes the
//      OTHER direction. Template<NKS> fallback to 28-ks (=R12) if the
//      163840 attribute opt-in is rejected.
// ---------------------------------------------------------------------------

#define H      1024
#define BATCH  64
#define T      256
#define RINGN  8

typedef _Float16 f16x8 __attribute__((ext_vector_type(8)));
typedef _Float16 f16x4 __attribute__((ext_vector_type(4)));
typedef float    f32x4 __attribute__((ext_vector_type(4)));

// ws layout (bytes)
#define WPACK_HH_SZ  (4ull*64*32*4*64*8*2)           // 33554432: [l][wg][ks][nt][lane][8] f16
#define WPACK_IH_SZ  (3ull*64*32*4*64*8*2)           // 25165824
#define HRING_OFF    (WPACK_HH_SZ + WPACK_IH_SZ)     // 58720256
#define SLOT_ELEMS   65536                           // per (l,slot): 64 batch x 1024 units f16
#define SLOT_BYTES   131072ull
#define CNT_INTS     (4*257*16)                      // flag/cnt2 region, 64B-padded entries
#define CNT_BYTES    ((unsigned long long)CNT_INTS*4)

__host__ __device__ __forceinline__ unsigned long long ring_bytes(int nslot) {
  return 4ull*(unsigned)nslot*SLOT_BYTES;
}
__device__ __forceinline__ int cidx(int l, int s) { return (l*257 + s)*16; }
// per-producer flag index: one 64B line per (layer, wg-block)
__device__ __forceinline__ int fidx(int l, int w) { return (l*64 + w)*16; }

// fresh mode: bit-reversed slot index kills any sequential-prefetch adjacency
__device__ __forceinline__ int aslot(int s, int fresh) {
  if (!fresh) return s & 7;
  return (s >= 256) ? 256 : (int)(__brev((unsigned)s) >> 24);
}

__device__ __forceinline__ void wait_eq64(int* p) {
  int it = 0;
  while (__hip_atomic_load(p, __ATOMIC_RELAXED, __HIP_MEMORY_SCOPE_AGENT) < 64) {
    __builtin_amdgcn_s_sleep(1);
    if (++it > 100000000) break;   // failsafe: never hang the harness
  }
}

// per-lane spin: lane waits until *p >= tgt (monotone flag)
__device__ __forceinline__ void wait_ge(const int* p, int tgt) {
  int it = 0;
  while (__hip_atomic_load(p, __ATOMIC_RELAXED, __HIP_MEMORY_SCOPE_AGENT) < tgt) {
    __builtin_amdgcn_s_sleep(1);
    if (++it > 100000000) break;   // failsafe: never hang the harness
  }
}

__device__ __forceinline__ f16x8 load_h8_sc(const _Float16* p) {
  const unsigned long long* q = (const unsigned long long*)p;
  unsigned long long lo = __hip_atomic_load(q,     __ATOMIC_RELAXED, __HIP_MEMORY_SCOPE_AGENT);
  unsigned long long hi = __hip_atomic_load(q + 1, __ATOMIC_RELAXED, __HIP_MEMORY_SCOPE_AGENT);
  union { unsigned long long u[2]; f16x8 v; } c;
  c.u[0] = lo; c.u[1] = hi;
  return c.v;
}

// --- pack weights fp32 -> fp16 MFMA-fragment layout; zero h ring slot 0; preset flags=0
__global__ void pack_kernel(const float* __restrict__ w_ih_rest,
                            const float* __restrict__ w_hh,
                            char* __restrict__ ws, int nslot)
{
  const long long NS_HH = 4ll*64*32*4*64;   // 2097152
  const long long NS_IH = 3ll*64*32*4*64;   // 1572864
  const long long NS_HZ = 4ll*8192;         // uint4 slots to zero slot-0 of each layer ring
  const long long NTOT  = NS_HH + NS_IH + NS_HZ + 256;
  _Float16* whh_dst = (_Float16*)ws;
  _Float16* wih_dst = (_Float16*)(ws + WPACK_HH_SZ);
  int* cnt = (int*)(ws + HRING_OFF + ring_bytes(nslot));
  for (long long i = blockIdx.x*(long long)blockDim.x + threadIdx.x; i < NTOT;
       i += (long long)gridDim.x*blockDim.x) {
    if (i < NS_HH + NS_IH) {
      const bool is_hh = (i < NS_HH);
      long long slot = is_hh ? i : (i - NS_HH);
      long long j = slot;
      int lane = (int)(j & 63); j >>= 6;
      int nt   = (int)(j & 3);  j >>= 2;
      int ks   = (int)(j & 31); j >>= 5;
      int wg   = (int)(j & 63); j >>= 6;
      int l    = (int)j;
      int row = nt*1024 + wg*16 + (lane & 15);      // global gate row (nt = gate: i,f,g,o)
      int col = ks*32 + (lane >> 4)*8;
      const float* src = (is_hh ? w_hh : w_ih_rest) + ((long long)l*4096 + row)*1024 + col;
      f16x8 v;
      #pragma unroll
      for (int e = 0; e < 8; e++) v[e] = (_Float16)src[e];
      *(f16x8*)((is_hh ? whh_dst : wih_dst) + slot*8) = v;
    } else if (i < NS_HH + NS_IH + NS_HZ) {
      long long j = i - (NS_HH + NS_IH);
      long long l = j >> 13;            // /8192
      long long off = j & 8191;
      uint4 z = make_uint4(0,0,0,0);
      ((uint4*)(ws + HRING_OFF))[(l*(long long)nslot)*8192 + off] = z;  // zero h[l][slot0]
    } else {
      int k = (int)(i - (NS_HH + NS_IH + NS_HZ));   // 0..255 = l*64+wg
      cnt[k*16] = 0;                                // flag: "step 0 published"
    }
  }
}

template <int NKS>   // #ks of w_hh staged in LDS (32 = full; 28 = R12 fallback)
__global__ __launch_bounds__(256, 1) void lstm_main(
    const float* __restrict__ x,
    const float* __restrict__ wih0,
    const float* __restrict__ bih,
    const float* __restrict__ bhh,
    char* __restrict__ ws, int nslot, int fresh)
{
  // one-time agent acquire: invalidate stale L1/L2 lines from prior replays
  __builtin_amdgcn_fence(__ATOMIC_ACQUIRE, "agent");

  extern __shared__ char lds[];
  _Float16* whh_lds = (_Float16*)lds;                          // NKS*4096 B
  _Float16* bufs    = (_Float16*)(lds + (size_t)NKS*4096);     // 4 x 8192 B partials

  const int l   = blockIdx.x >> 6;
  const int wg  = blockIdx.x & 63;
  const int tid = threadIdx.x;
  const int wave = tid >> 6;
  const int lane = tid & 63;

  const _Float16* wpack_hh = (const _Float16*)ws + (size_t)(l*64 + wg)*65536;
  const _Float16* wpack_ih = (l > 0)
      ? (const _Float16*)(ws + WPACK_HH_SZ) + (size_t)((l-1)*64 + wg)*65536
      : wpack_hh;  // unused for l==0
  _Float16* hring = (_Float16*)(ws + HRING_OFF);
  int* cnt  = (int*)(ws + HRING_OFF + ring_bytes(nslot));   // per-producer flags
  int* cnt2 = cnt + CNT_INTS;                               // fallback backpressure (atomic)

  // stage w_hh ks 0..NKS-1 into LDS (one-time; wpack is immutable; ks-major)
  {
    const uint4* src = (const uint4*)wpack_hh;
    uint4* dst = (uint4*)whh_lds;
    for (int i = tid; i < NKS*256; i += 256) dst[i] = src[i];
  }

  // elementwise ownership: thread -> (batch b_ew, 4 consecutive hidden units u0..u0+3)
  const int b_ew = tid >> 2;
  const int u0   = (tid & 3) * 4;
  float cst[4] = {0.f, 0.f, 0.f, 0.f};
  float bias[4][4];            // [item][gate]
  float wx0[4][4], wx1[4][4];  // layer-0 input weights (K=2 handled in VALU)
  #pragma unroll
  for (int ii = 0; ii < 4; ii++) {
    #pragma unroll
    for (int g = 0; g < 4; g++) {
      int row = g*1024 + wg*16 + u0 + ii;
      bias[ii][g] = bih[l*4096 + row] + bhh[l*4096 + row];
      if (l == 0) { wx0[ii][g] = wih0[row*2]; wx1[ii][g] = wih0[row*2 + 1]; }
      else        { wx0[ii][g] = 0.f;         wx1[ii][g] = 0.f; }
    }
  }
  __syncthreads();

  const int m_row = lane & 15, quad = lane >> 4;

  for (int s = 1; s <= T; s++) {
    if (fresh) {
      // per-wave dataflow waits; NO pre-GEMM barrier. Each wave polls only
      // the producer chunks its GEMM segment actually reads.
      if (l == 0) {
        if (lane < 16) wait_ge(cnt + fidx(0, wave*16 + lane), s - 1);
      } else {
        if (wave == 0)      { if (lane < 32) wait_ge(cnt + fidx(l-1, lane),      s); }
        else if (wave == 1) { if (lane < 32) wait_ge(cnt + fidx(l-1, 32 + lane), s); }
        else if (wave == 2) { if (lane < 32) wait_ge(cnt + fidx(l,   lane),      s - 1); }
        else                { if (lane < 32) wait_ge(cnt + fidx(l,   32 + lane), s - 1); }
      }
    } else {
      // fallback: wide waits + barrier (ring-reuse mode)
      if (wave == 0) {
        wait_ge(cnt + fidx(l, lane), s - 1);
      } else if (wave == 1) {
        if (l > 0) wait_ge(cnt + fidx(l - 1, lane), s);
      } else if (tid == 128) {
        if (l < 3 && s > RINGN) wait_eq64(&cnt2[cidx(l, s-RINGN)]);
      }
      __syncthreads();
    }

    // A source: for l>0 waves 0-1 consume h_below[s] (with w_ih), waves 2-3 h_own[s-1] (w_hh)
    const _Float16* asrc = (l > 0 && wave < 2)
        ? hring + ((size_t)(l-1)*nslot + aslot(s,   fresh))*SLOT_ELEMS
        : hring + ((size_t)l*nslot     + aslot(s-1, fresh))*SLOT_ELEMS;

    f32x4 acc[4][4];
    #pragma unroll
    for (int mt = 0; mt < 4; mt++)
      #pragma unroll
      for (int nt = 0; nt < 4; nt++) acc[mt][nt] = (f32x4){0.f, 0.f, 0.f, 0.f};

    // b from LDS (w_hh ks<NKS)
    auto kb_lds = [&](int ks, bool plain) {
      const int kb = ks*32 + quad*8;
      f16x8 a[4], bb[4];
      #pragma unroll
      for (int mt = 0; mt < 4; mt++) {
        const _Float16* ap = asrc + (size_t)(mt*16 + m_row)*1024 + kb;
        a[mt] = plain ? *(const f16x8*)ap : load_h8_sc(ap);
      }
      #pragma unroll
      for (int nt = 0; nt < 4; nt++)
        bb[nt] = *(const f16x8*)(whh_lds + ((ks*4 + nt)*64 + lane)*8);
      #pragma unroll
      for (int mt = 0; mt < 4; mt++)
        #pragma unroll
        for (int nt = 0; nt < 4; nt++)
          acc[mt][nt] = __builtin_amdgcn_mfma_f32_16x16x32_f16(a[mt], bb[nt], acc[mt][nt], 0, 0, 0);
    };
    // b from global (w_ih stream, or w_hh spill ks>=NKS in fallback template)
    auto kb_glob = [&](int ks, const _Float16* bsrc, bool plain) {
      const int kb = ks*32 + quad*8;
      f16x8 a[4], bb[4];
      #pragma unroll
      for (int mt = 0; mt < 4; mt++) {
        const _Float16* ap = asrc + (size_t)(mt*16 + m_row)*1024 + kb;
        a[mt] = plain ? *(const f16x8*)ap : load_h8_sc(ap);
      }
      #pragma unroll
      for (int nt = 0; nt < 4; nt++)
        bb[nt] = *(const f16x8*)(bsrc + ((size_t)(ks*4 + nt)*64 + lane)*8);
      #pragma unroll
      for (int mt = 0; mt < 4; mt++)
        #pragma unroll
        for (int nt = 0; nt < 4; nt++)
          acc[mt][nt] = __builtin_amdgcn_mfma_f32_16x16x32_f16(a[mt], bb[nt], acc[mt][nt], 0, 0, 0);
    };

    const bool pl = (fresh != 0);
    if (l == 0) {
      if (NKS >= 32 || wave < 3) {
        #pragma unroll 4
        for (int i = 0; i < 8; i++) kb_lds(wave*8 + i, pl);
      } else {  // NKS==28, wave 3: ks 24..27 LDS, 28..31 global
        #pragma unroll 4
        for (int i = 0; i < 4; i++) kb_lds(24 + i, pl);
        #pragma unroll
        for (int i = 0; i < 4; i++) kb_glob(28 + i, wpack_hh, pl);
      }
    } else if (wave < 2) {
      #pragma unroll 4
      for (int i = 0; i < 16; i++) kb_glob(wave*16 + i, wpack_ih, pl);
    } else if (wave == 2) {
      #pragma unroll 4
      for (int i = 0; i < 16; i++) kb_lds(i, pl);
    } else {
      #pragma unroll 4
      for (int i = 0; i < (NKS - 16); i++) kb_lds(16 + i, pl);
      #pragma unroll
      for (int i = NKS - 16; i < 16; i++) kb_glob(16 + i, wpack_hh, pl);
    }

    // every wave writes its own partial buffer (no add pass)
    {
      _Float16* mybuf = bufs + (size_t)wave*4096;   // 8192 B each
      #pragma unroll
      for (int mt = 0; mt < 4; mt++)
        #pragma unroll
        for (int nt = 0; nt < 4; nt++) {
          f16x4 v;
          #pragma unroll
          for (int e = 0; e < 4; e++) v[e] = (_Float16)acc[mt][nt][e];
          *(f16x4*)(mybuf + ((mt*4 + nt)*64 + lane)*4) = v;
        }
    }
    // ring backpressure signal only needed when slots are reused (fallback mode)
    if (!fresh && tid == 0 && l > 0)
      __hip_atomic_fetch_add(&cnt2[cidx(l-1, s)], 1, __ATOMIC_RELAXED, __HIP_MEMORY_SCOPE_AGENT);
    __syncthreads();   // bar1: all partials visible (also: h reads complete)

    // elementwise gates -> c,h  (fp32); sums 4 partial bufs directly
    {
      const int mt = b_ew >> 4, q = (b_ew & 15) >> 2, reg = b_ew & 3;
      float xs0 = 0.f, xs1 = 0.f;
      if (l == 0) {
        xs0 = x[((size_t)b_ew*T + (s-1))*2];
        xs1 = x[((size_t)b_ew*T + (s-1))*2 + 1];
      }
      f16x4 hv;
      #pragma unroll
      for (int ii = 0; ii < 4; ii++) {
        const int u = u0 + ii;
        float pre[4];
        #pragma unroll
        for (int g = 0; g < 4; g++) {
          int idx = ((mt*4 + g)*64 + (u + 16*q))*4 + reg;
          pre[g] = (float)bufs[idx] + (float)bufs[4096 + idx]
                 + (float)bufs[8192 + idx] + (float)bufs[12288 + idx]
                 + bias[ii][g] + wx0[ii][g]*xs0 + wx1[ii][g]*xs1;
        }
        float ig = 1.f/(1.f + __expf(-pre[0]));
        float fg = 1.f/(1.f + __expf(-pre[1]));
        float gg = 2.f/(1.f + __expf(-2.f*pre[2])) - 1.f;
        float og = 1.f/(1.f + __expf(-pre[3]));
        float c  = fg*cst[ii] + ig*gg;
        cst[ii] = c;
        float th = 2.f/(1.f + __expf(-2.f*c)) - 1.f;
        hv[ii] = (_Float16)(og*th);
      }
      _Float16* hdst = hring + ((size_t)l*nslot + aslot(s, fresh))*SLOT_ELEMS
                     + (size_t)b_ew*1024 + wg*16 + u0;
      union { f16x4 v; unsigned long long u; } cv; cv.v = hv;
      // sc write-through: IF$ (coherence point) holds the authoritative copy
      __hip_atomic_store((unsigned long long*)hdst, cv.u,
                         __ATOMIC_RELAXED, __HIP_MEMORY_SCOPE_AGENT);
    }
    __syncthreads();   // bar2: h stores acked at coherence point before flag;
                       // also guards partial-buf reuse for step s+1
    if (tid == 0)      // plain sc store publish: no RMW, per-producer line
      __hip_atomic_store(cnt + fidx(l, wg), s,
                         __ATOMIC_RELAXED, __HIP_MEMORY_SCOPE_AGENT);
  }
}

__global__ void fc_kernel(const char* __restrict__ ws,
                          const float* __restrict__ fcw,
                          const float* __restrict__ fcb,
                          float* __restrict__ out, int nslot, int fresh)
{
  const _Float16* h3 = (const _Float16*)(ws + HRING_OFF)
                     + ((size_t)3*nslot + aslot(T, fresh))*SLOT_ELEMS;  // layer 3, t=256
  __shared__ float red[256];
  const int tid = threadIdx.x;
  const int b = tid >> 2, p = tid & 3;
  float sum = 0.f;
  for (int j = p*256; j < p*256 + 256; j++)
    sum += fcw[j] * (float)h3[(size_t)b*1024 + j];
  red[tid] = sum;
  __syncthreads();
  if (p == 0)
    out[b] = red[tid] + red[tid+1] + red[tid+2] + red[tid+3] + fcb[0];
}

extern "C" void kernel_launch(void* const* d_in, const int* in_sizes, int n_in,
                              void* d_out, int out_size, void* d_ws, size_t ws_size,
                              hipStream_t stream)
{
  const float* x    = (const float*)d_in[0];
  const float* wih0 = (const float*)d_in[1];
  const float* wihr = (const float*)d_in[2];
  const float* whh  = (const float*)d_in[3];
  const float* bih  = (const float*)d_in[4];
  const float* bhh  = (const float*)d_in[5];
  const float* fcw  = (const float*)d_in[6];
  const float* fcb  = (const float*)d_in[7];
  float* out = (float*)d_out;
  char* ws = (char*)d_ws;
  (void)in_sizes; (void)n_in; (void)out_size;

  const unsigned long long ws_big   = HRING_OFF + ring_bytes(257) + 2*CNT_BYTES; // ~193.6 MB
  const unsigned long long ws_small = HRING_OFF + ring_bytes(8)   + 2*CNT_BYTES; // ~63 MB
  if (ws_size < ws_small) return;
  const int fresh = (ws_size >= ws_big) ? 1 : 0;
  const int nslot = fresh ? 257 : 8;

  // try full 160 KiB workgroup LDS (32-ks w_hh + partials); fall back to R12's
  // 147456 (28-ks) if the opt-in is rejected. Host-side, idempotent,
  // capture-safe.
  hipError_t eFull = hipFuncSetAttribute(
      reinterpret_cast<const void*>(lstm_main<32>),
      hipFuncAttributeMaxDynamicSharedMemorySize, 163840);
  if (eFull != hipSuccess)
    hipFuncSetAttribute(reinterpret_cast<const void*>(lstm_main<28>),
                        hipFuncAttributeMaxDynamicSharedMemorySize, 147456);

  hipMemsetAsync(ws + HRING_OFF + ring_bytes(nslot), 0, (size_t)(2*CNT_BYTES), stream);
  pack_kernel<<<512, 256, 0, stream>>>(wihr, whh, ws, nslot);
  if (eFull == hipSuccess)
    lstm_main<32><<<256, 256, 163840, stream>>>(x, wih0, bih, bhh, ws, nslot, fresh);
  else
    lstm_main<28><<<256, 256, 147456, stream>>>(x, wih0, bih, bhh, ws, nslot, fresh);
  fc_kernel<<<1, 256, 0, stream>>>(ws, fcw, fcb, out, nslot, fresh);
}